// Round 1
// baseline (166.987 us; speedup 1.0000x reference)
//
#include <hip/hip_runtime.h>

#define T_TOT 1000
#define NCLS  100
#define BATCH 256
#define LOG_T 6.90775527898213705f   // ln(1000)

// sigma = exp(0.5 * log_sigma2), precomputed once (25600 elements)
__global__ __launch_bounds__(256) void sigma_kernel(const float* __restrict__ ls2,
                                                    float* __restrict__ sigma) {
    int i = blockIdx.x * 256 + threadIdx.x;
    if (i < BATCH * NCLS) sigma[i] = __expf(0.5f * ls2[i]);
}

// One 32-lane half-wave per (t,b) row. Lane j owns classes 4j..4j+3 (float4).
// Produces v[b*T + t] = logits[t,b,y_b] - logsumexp_c(logits[t,b,:])
__global__ __launch_bounds__(256) void rows_kernel(const float* __restrict__ mu,
                                                   const float* __restrict__ sigma,
                                                   const float* __restrict__ eps,
                                                   const int* __restrict__ y,
                                                   float* __restrict__ v_ws) {
    const int lane = threadIdx.x & 63;
    const int half = lane >> 5;          // which 32-lane half of the wave
    const int j    = lane & 31;          // lane within half
    const int wid  = (blockIdx.x * blockDim.x + threadIdx.x) >> 6;  // global wave id
    const int nw   = (gridDim.x * blockDim.x) >> 6;
    const int total_pairs = (T_TOT * BATCH) / 2;   // 2 rows per wave

    for (int pair = wid; pair < total_pairs; pair += nw) {
        const int r = pair * 2 + half;        // row = t*B + b
        const int b = r & (BATCH - 1);
        const int t = r >> 8;                 // B == 256

        float x0 = -INFINITY, x1 = -INFINITY, x2 = -INFINITY, x3 = -INFINITY;
        if (j < 25) {                          // 25 lanes * 4 = 100 classes
            const float4 e4 = *(const float4*)(eps + (size_t)r * NCLS + 4 * j);
            const float4 m4 = *(const float4*)(mu  + b * NCLS + 4 * j);
            const float4 s4 = *(const float4*)(sigma + b * NCLS + 4 * j);
            x0 = fmaf(s4.x, e4.x, m4.x);
            x1 = fmaf(s4.y, e4.y, m4.y);
            x2 = fmaf(s4.z, e4.z, m4.z);
            x3 = fmaf(s4.w, e4.w, m4.w);
        }

        // row max (butterfly within each 32-lane half; xor offsets <32 stay in-half)
        float m = fmaxf(fmaxf(x0, x1), fmaxf(x2, x3));
        #pragma unroll
        for (int off = 1; off <= 16; off <<= 1)
            m = fmaxf(m, __shfl_xor(m, off, 64));

        // sum of exp(x - m); inactive lanes hold -inf -> exp = 0
        float s = __expf(x0 - m) + __expf(x1 - m) + __expf(x2 - m) + __expf(x3 - m);
        #pragma unroll
        for (int off = 1; off <= 16; off <<= 1)
            s += __shfl_xor(s, off, 64);

        // fetch logits[t,b,y_b]: it lives in component (y&3) of lane (y>>2) of this half
        const int yb = y[b];
        const int ks = yb & 3;
        const float sel = (ks == 0) ? x0 : (ks == 1) ? x1 : (ks == 2) ? x2 : x3;
        const float px = __shfl(sel, (half << 5) + (yb >> 2), 64);

        if (j == 0) v_ws[b * T_TOT + t] = px - (m + __logf(s));
    }
}

// One block per b: logsumexp over the contiguous 1000 v's, atomic -mean into out.
__global__ __launch_bounds__(256) void lse_kernel(const float* __restrict__ v_ws,
                                                  float* __restrict__ out) {
    const int b = blockIdx.x;
    const float* vb = v_ws + b * T_TOT;
    const int tid = threadIdx.x;

    float m = -INFINITY;
    for (int t = tid; t < T_TOT; t += 256) m = fmaxf(m, vb[t]);
    #pragma unroll
    for (int off = 1; off <= 32; off <<= 1) m = fmaxf(m, __shfl_xor(m, off, 64));

    __shared__ float red[8];
    const int wv = tid >> 6;
    if ((tid & 63) == 0) red[wv] = m;
    __syncthreads();
    m = fmaxf(fmaxf(red[0], red[1]), fmaxf(red[2], red[3]));

    float s = 0.f;
    for (int t = tid; t < T_TOT; t += 256) s += __expf(vb[t] - m);
    #pragma unroll
    for (int off = 1; off <= 32; off <<= 1) s += __shfl_xor(s, off, 64);
    if ((tid & 63) == 0) red[4 + wv] = s;
    __syncthreads();

    if (tid == 0) {
        const float ssum = red[4] + red[5] + red[6] + red[7];
        const float logp = m + __logf(ssum) - LOG_T;
        atomicAdd(out, -logp * (1.0f / BATCH));
    }
}

extern "C" void kernel_launch(void* const* d_in, const int* in_sizes, int n_in,
                              void* d_out, int out_size, void* d_ws, size_t ws_size,
                              hipStream_t stream) {
    const float* mu  = (const float*)d_in[0];
    const float* ls2 = (const float*)d_in[1];
    const float* eps = (const float*)d_in[2];
    const int*   y   = (const int*)d_in[3];
    float* out   = (float*)d_out;
    float* sigma = (float*)d_ws;                 // 25600 floats
    float* v_ws  = sigma + BATCH * NCLS;         // 256000 floats

    hipMemsetAsync(out, 0, sizeof(float), stream);
    sigma_kernel<<<(BATCH * NCLS + 255) / 256, 256, 0, stream>>>(ls2, sigma);
    rows_kernel<<<2048, 256, 0, stream>>>(mu, sigma, eps, y, v_ws);
    lse_kernel<<<BATCH, 256, 0, stream>>>(v_ws, out);
}